// Round 11
// baseline (192.703 us; speedup 1.0000x reference)
//
#include <hip/hip_runtime.h>

#define B_TOT 65536
#define T_STEPS 10
#define D_IN 16
#define H 64
#define G4H 256
#define D_MLP 30
#define D_OUT 4
#define BTILE 32
#define PSTR 72     // h-plane row stride (shorts): 144B rows -> ds_read_b128 ALIGNED; 36dw -> 2-way only
#define DSTR 32     // d buffer row stride (shorts): 64B rows -> aligned + contiguous ad reads
#define LOG2E 1.44269504088896340736f
#define TWO_LOG2E 2.88539008177792681472f

typedef short short8 __attribute__((ext_vector_type(8)));
typedef float float4_t __attribute__((ext_vector_type(4)));
typedef __bf16 bf16x8_t __attribute__((ext_vector_type(8)));

static __device__ __forceinline__ short f2bf(float f) {  // round-half-up (activations)
    unsigned u = __builtin_bit_cast(unsigned, f);
    return (short)(unsigned short)((u + 0x8000u) >> 16);
}
static __device__ __forceinline__ short f2bf_rne(float f) {  // weights
    unsigned u = __builtin_bit_cast(unsigned, f);
    unsigned r = (u + 0x7FFFu + ((u >> 16) & 1u)) >> 16;
    return (short)(unsigned short)r;
}
static __device__ __forceinline__ float bf2f(short s) {
    unsigned u = ((unsigned)(unsigned short)s) << 16;
    return __builtin_bit_cast(float, u);
}
static __device__ __forceinline__ float4_t mfma16(short8 a, short8 b, float4_t c) {
    return __builtin_amdgcn_mfma_f32_16x16x32_bf16(
        __builtin_bit_cast(bf16x8_t, a), __builtin_bit_cast(bf16x8_t, b), c, 0, 0, 0);
}
// pack two f32 -> one dword of 2 bf16 (round-half-up, same bits as f2bf pairwise)
static __device__ __forceinline__ unsigned pk2bf(float lo, float hi) {
    const unsigned ulo = __builtin_bit_cast(unsigned, lo) + 0x8000u;
    const unsigned uhi = __builtin_bit_cast(unsigned, hi) + 0x8000u;
    return (ulo >> 16) | (uhi & 0xFFFF0000u);
}

// ---- workspace layout (bytes) ----
#define WS_WU1 0        // 48 frags x 1KB = 49152
#define WS_WU2 49152    // 48 frags = 49152
#define WS_WD  98304    // 4 frags = 4096
#define WS_BDP 102400   // 32 f32
#define WS_DG  114688   // global D overflow region

// Weights pre-swizzled to MFMA B-frag order (frag f, lane l, elem e -> B[k=(l>>4)*8+e][n=l&15])
// and pre-scaled: i/f/o gates by log2e, L1 g-gate by 2*log2e, L2 g-gate (relu) raw.
// TRANSPOSE DUALITY (r7/r9): the same register bits serve as an A-frag of U^T, so
// z^T = mfma(wz, h_frag) and d^T = mfma(wd, h_frag) need NO new layouts.
// BIAS FOLDING (r5): b1 in wu1 kt2 row k=16 (activated by 1.0 in ax); b2 in wu2 kt0 row
// k=30 (activated by d[...,30]==1.0 via bdp[30]=1.0).
// wu1: A1=[h1(0:64)|x(16)|1|0...], kt0=U1[0:32], kt1=U1[32:64], kt2=[W1(16);b1;zeros(15)]
// wu2: A2=[d(0:30)|1|0|h2(0:64)], kt0=[W2(30);b2;0], kt1=U2[0:32], kt2=U2[32:64]
// wd : d = h1 @ Wd (cols padded 30->32, col30 forced to 1.0 via bdp), unscaled
__global__ void precompute(const float* __restrict__ W1, const float* __restrict__ U1,
                           const float* __restrict__ b1, const float* __restrict__ Wd,
                           const float* __restrict__ bd, const float* __restrict__ W2,
                           const float* __restrict__ U2, const float* __restrict__ b2,
                           short* __restrict__ wu1_sw, short* __restrict__ wu2_sw,
                           short* __restrict__ wd_sw, float* __restrict__ bdp) {
    const int lane = threadIdx.x;  // 64
    const int b = blockIdx.x;      // 101
    if (b < 48) {
        const int f = b, jt = f / 12, g = (f / 3) & 3, kt = f % 3;
        const int col = g * 64 + jt * 16 + (lane & 15);
        const float sc = (g == 2) ? TWO_LOG2E : LOG2E;
        for (int e = 0; e < 8; ++e) {
            const int sub = (lane >> 4) * 8 + e;  // 0..31
            float v;
            if (kt == 0)      v = U1[sub * G4H + col];
            else if (kt == 1) v = U1[(sub + 32) * G4H + col];
            else              v = (sub < 16) ? W1[sub * G4H + col]
                                             : ((sub == 16) ? b1[col] : 0.0f);
            wu1_sw[(f * 64 + lane) * 8 + e] = f2bf_rne(v * sc);
        }
    } else if (b < 96) {
        const int f = b - 48, jt = f / 12, g = (f / 3) & 3, kt = f % 3;
        const int col = g * 64 + jt * 16 + (lane & 15);
        const float sc = (g == 2) ? 1.0f : LOG2E;  // relu gate stays raw
        for (int e = 0; e < 8; ++e) {
            const int sub = (lane >> 4) * 8 + e;
            float v;
            if (kt == 0)      v = (sub < D_MLP) ? W2[sub * G4H + col]
                                                : ((sub == D_MLP) ? b2[col] : 0.0f);
            else if (kt == 1) v = U2[sub * G4H + col];
            else              v = U2[(sub + 32) * G4H + col];
            wu2_sw[(f * 64 + lane) * 8 + e] = f2bf_rne(v * sc);
        }
    } else if (b < 100) {
        const int fd = b - 96, nt = fd >> 1, kt = fd & 1;
        const int col = nt * 16 + (lane & 15);
        for (int e = 0; e < 8; ++e) {
            const int k = kt * 32 + (lane >> 4) * 8 + e;  // h1 dim 0..63
            const float v = (col < D_MLP) ? Wd[k * D_MLP + col] : 0.0f;
            wd_sw[(fd * 64 + lane) * 8 + e] = f2bf_rne(v);
        }
    } else {
        // bdp: dense bias cols 0..29; col 30 = 1.0 (phase-2 bias activator); col 31 = 0
        if (lane < 32)
            bdp[lane] = (lane < D_MLP) ? bd[lane] : ((lane == D_MLP) ? 1.0f : 0.0f);
    }
}

// ---------------- r11: SPILL-FREE 64-reg body @ LDS 19456 (the clean 8-block test) ----------
// r10 evidence: LDS cap lifted to 8 blocks/CU but occupancy pinned at ~35% with ~39MB spill.
// Hypothesis: scratch-using dispatches are residency-capped (~5 blocks); the spill blocks the
// occupancy it was meant to buy. r11 removes ~20 regs of persistent/peak pressure:
//  1. JIT x-frag (px prefetch dropped; load x[t] where consumed)           -8 persistent
//  2. wd frag loads moved AFTER the gate barrier (issued at point of use)  -8 during peak
//  3. bdv (d-proj bias) reloaded per t at d-proj                           -4 persistent
// Body otherwise r10 verbatim. SIGNAL: WRITE_SIZE ~22-26MB (pure D+out, no spill).
// FORK: occupancy >=50 -> hypothesis true, dur ~92-102; occupancy ~35 + dur ~110 ->
// plateau is structural, declare ceiling next round.
template <int DLDS>
__global__ __launch_bounds__(256)
__attribute__((amdgpu_waves_per_eu(4, 8)))
void lstm_all_t(const float* __restrict__ x, const short* __restrict__ wu1_sw,
                const short* __restrict__ wu2_sw, const short* __restrict__ wd_sw,
                const float* __restrict__ bdp, const float* __restrict__ Wf,
                const float* __restrict__ bfin, short* __restrict__ Dg,
                float* __restrict__ out) {
    __shared__ __align__(16) short P[2][BTILE * PSTR];       // 9216 B
    __shared__ __align__(16) short Dl[DLDS][BTILE * DSTR];   // DLDS=5: 10240 B -> total 19456
    const int tid = threadIdx.x, lane = tid & 63, wave = tid >> 6;
    const int q = lane >> 4, n = lane & 15;
    const int b0 = blockIdx.x * BTILE;
    short* const dgb = Dg + (size_t)blockIdx.x * ((T_STEPS - DLDS) * BTILE * DSTR);

    // ---- phase-1 weights: wave owns gate-col slice [g*64 + wave*16, +16) ----
    short8 wz[4][3];
#pragma unroll
    for (int g = 0; g < 4; ++g)
#pragma unroll
        for (int kt = 0; kt < 3; ++kt)
            wz[g][kt] = ((const short8*)wu1_sw)[(wave * 12 + g * 3 + kt) * 64 + lane];

    // d-projection tile assignment (wd/bdv values are loaded per-t at the point of use)
    const int mw = (wave >> 1) & 1, ntw = wave & 1;

    // bias activator for the ax frag: lanes 32..47 (q==2) elem0 = bf16(1.0), else 0
    const unsigned bias0 = (lane >= 32 && lane < 48) ? 0x00003F80u : 0u;
    const bool hb = (lane >= 32);

    for (int i = tid; i < BTILE * PSTR; i += 256) P[0][i] = 0;

    float4_t cc[2];
    cc[0] = (float4_t){0, 0, 0, 0};
    cc[1] = (float4_t){0, 0, 0, 0};

    // x address, lane-packed: lane<32 -> m=0 rows (b0+n), lane>=32 -> m=1 rows (b0+16+n)
    const float* xlane = x + (size_t)(b0 + (lane >> 5) * 16 + n) * (T_STEPS * D_IN)
                           + ((lane >> 4) & 1) * 8;
    __syncthreads();  // P[0] zeros visible

    // ================= phase 1: LSTM1 (tanh) + Dense into Dl/Dg =================
    for (int t = 0; t < T_STEPS; ++t) {
        const short* cb = P[t & 1];
        short* nb = P[(t & 1) ^ 1];

        // JIT x frags: load x[t] here, pack, exchange; registers die within the iteration.
        // lanes>=32 masked to the bias pattern (1.0 at k=16 for q==2).
        const float4 p0 = *(const float4*)(xlane + t * D_IN);
        const float4 p1 = *(const float4*)(xlane + t * D_IN + 4);
        uint4 axu;
        axu.x = pk2bf(p0.x, p0.y);
        axu.y = pk2bf(p0.z, p0.w);
        axu.z = pk2bf(p1.x, p1.y);
        axu.w = pk2bf(p1.z, p1.w);
        uint4 axv;
        axv.x = __shfl_xor((int)axu.x, 32);
        axv.y = __shfl_xor((int)axu.y, 32);
        axv.z = __shfl_xor((int)axu.z, 32);
        axv.w = __shfl_xor((int)axu.w, 32);
        const uint4 bmask = (uint4){bias0, 0u, 0u, 0u};
        short8 axm[2];
        axm[0] = __builtin_bit_cast(short8, hb ? bmask : axu);
        axm[1] = __builtin_bit_cast(short8, hb ? bmask : axv);

#pragma unroll
        for (int m = 0; m < 2; ++m) {
            const int arow = (16 * m + n) * PSTR + q * 8;
            const short8 ah0 = *(const short8*)&cb[arow];
            const short8 ah1 = *(const short8*)&cb[arow + 32];
            float4_t ac[4];
#pragma unroll
            for (int g = 0; g < 4; ++g) {
                // SWAPPED: ac[g][jj] = gate g of cell (batch=16m+n, hcol=wave*16+q*4+jj)
                float4_t c = (float4_t){0, 0, 0, 0};
                c = mfma16(wz[g][0], ah0, c);
                c = mfma16(wz[g][1], ah1, c);
                c = mfma16(wz[g][2], axm[m], c);   // includes +b1 via k=16
                ac[g] = c;
            }
            // merged-rcp activation: 5 exp2 + 2 rcp per cell.
            float hv[4];
#pragma unroll
            for (int jj = 0; jj < 4; ++jj) {
                const float Bv = __builtin_amdgcn_exp2f(-ac[0][jj]);
                const float Fv = __builtin_amdgcn_exp2f(-ac[1][jj]);
                const float Qv = __builtin_amdgcn_exp2f(ac[2][jj]);
                const float Av = __builtin_amdgcn_exp2f(-ac[3][jj]);
                const float uu = (1.0f + Bv) * (Qv + 1.0f);
                const float vv = 1.0f + Fv;
                const float num = cc[m][jj] * uu + (Qv - 1.0f) * vv;
                const float cn = num * __builtin_amdgcn_rcpf(uu * vv);
                cc[m][jj] = cn;
                const float Pv = __builtin_amdgcn_exp2f(cn * TWO_LOG2E);
                const float ww = (1.0f + Av) * (Pv + 1.0f);
                hv[jj] = (Pv - 1.0f) * __builtin_amdgcn_rcpf(ww);
            }
            *(uint2*)&nb[(16 * m + n) * PSTR + wave * 16 + q * 4] =
                (uint2){pk2bf(hv[0], hv[1]), pk2bf(hv[2], hv[3])};
        }
        __syncthreads();  // h1_t complete

        // d_t^T = mfma(wd, h) (transpose duality). wd frags + bias loaded HERE (L2-hot,
        // 4KB/128B tables) so they are not live through the gate/activation peak.
        // Thread holds d-cols ntw*16+q*4..+3 of batch row 16mw+n -> one 8B store;
        // t<DLDS -> LDS, else workspace. dcol 30 gets 0+1.0 -> exact bf16 1.0 (bias activator).
        {
            const short8* wp = (const short8*)wd_sw + (ntw * 2) * 64 + lane;
            asm volatile("" : "+v"(wp));
            const short8 wda = wp[0];
            const short8 wdb = wp[64];
            const float* bp = &bdp[ntw * 16 + q * 4];
            asm volatile("" : "+v"(bp));
            const float4 bdvv = *(const float4*)bp;

            const int drow = (16 * mw + n) * PSTR + q * 8;
            const short8 dh0 = *(const short8*)&nb[drow];
            const short8 dh1 = *(const short8*)&nb[drow + 32];
            float4_t dd = (float4_t){bdvv.x, bdvv.y, bdvv.z, bdvv.w};
            dd = mfma16(wda, dh0, dd);
            dd = mfma16(wdb, dh1, dd);
            const uint2 dpk = (uint2){pk2bf(dd[0], dd[1]), pk2bf(dd[2], dd[3])};
            const int doff = (16 * mw + n) * DSTR + ntw * 16 + q * 4;
            if (t < DLDS)
                *(uint2*)&Dl[t][doff] = dpk;
            else
                *(uint2*)&dgb[(t - DLDS) * (BTILE * DSTR) + doff] = dpk;
        }
    }

    // ================= phase boundary =================
    __syncthreads();  // drains Dg stores (vmcnt) + all P reads before re-zeroing
#pragma unroll
    for (int g = 0; g < 4; ++g)
#pragma unroll
        for (int kt = 0; kt < 3; ++kt)
            wz[g][kt] = ((const short8*)wu2_sw)[(wave * 12 + g * 3 + kt) * 64 + lane];
    cc[0] = (float4_t){0, 0, 0, 0};
    cc[1] = (float4_t){0, 0, 0, 0};
    for (int i = tid; i < BTILE * PSTR; i += 256) P[0][i] = 0;
    __syncthreads();

    // ================= phase 2: LSTM2 (relu) from Dl/Dg =================
    for (int t = 0; t < T_STEPS; ++t) {
        const short* cb = P[t & 1];
        short* nb = P[(t & 1) ^ 1];

        // both m rows' d frags issued together (16B/lane, LDS or L2-hot coalesced)
        uint4 adu0, adu1;
        if (t < DLDS) {
            adu0 = *(const uint4*)&Dl[t][n * DSTR + q * 8];
            adu1 = *(const uint4*)&Dl[t][(16 + n) * DSTR + q * 8];
        } else {
            const short* dgt = dgb + (t - DLDS) * (BTILE * DSTR);
            adu0 = *(const uint4*)&dgt[n * DSTR + q * 8];
            adu1 = *(const uint4*)&dgt[(16 + n) * DSTR + q * 8];
        }
        short8 adm[2];
        adm[0] = __builtin_bit_cast(short8, adu0);
        adm[1] = __builtin_bit_cast(short8, adu1);

#pragma unroll
        for (int m = 0; m < 2; ++m) {
            const int ar = 16 * m + n;
            const short8 ah0 = *(const short8*)&cb[ar * PSTR + q * 8];
            const short8 ah1 = *(const short8*)&cb[ar * PSTR + 32 + q * 8];
            float4_t ac[4];
#pragma unroll
            for (int g = 0; g < 4; ++g) {
                float4_t c = (float4_t){0, 0, 0, 0};
                c = mfma16(wz[g][0], adm[m], c);   // includes +b2 via dcol30==1.0 x W2 row30
                c = mfma16(wz[g][1], ah0, c);
                c = mfma16(wz[g][2], ah1, c);
                ac[g] = c;
            }
            // single-rcp relu activation (r8-validated): 3 exp2 + 1 rcp per cell.
            float hv[4];
#pragma unroll
            for (int jj = 0; jj < 4; ++jj) {
                const float Bv = __builtin_amdgcn_exp2f(-ac[0][jj]);
                const float Fv = __builtin_amdgcn_exp2f(-ac[1][jj]);
                const float gp = fmaxf(ac[2][jj], 0.0f);
                const float Av = __builtin_amdgcn_exp2f(-ac[3][jj]);
                const float eb = 1.0f + Bv, ef = 1.0f + Fv, ea = 1.0f + Av;
                const float num = cc[m][jj] * eb + gp * ef;
                const float R = __builtin_amdgcn_rcpf(eb * ef * ea);
                cc[m][jj] = num * ea * R;
                hv[jj] = fmaxf(num, 0.0f) * R;
            }
            *(uint2*)&nb[ar * PSTR + wave * 16 + q * 4] =
                (uint2){pk2bf(hv[0], hv[1]), pk2bf(hv[2], hv[3])};
        }
        __syncthreads();
    }

    // ---- out = h2_9 @ Wf + bf ; t=9 wrote nb = P[0] ----
    if (tid < 128) {
        const int r = tid >> 2, c = tid & 3;
        float s = bfin[c];
#pragma unroll
        for (int kb = 0; kb < 8; ++kb) {
            const short8 h8 = *(const short8*)&P[0][r * PSTR + kb * 8];
#pragma unroll
            for (int e = 0; e < 8; ++e)
                s += bf2f(h8[e]) * Wf[(kb * 8 + e) * D_OUT + c];
        }
        out[(size_t)(b0 + r) * D_OUT + c] = s;
    }
}

extern "C" void kernel_launch(void* const* d_in, const int* in_sizes, int n_in,
                              void* d_out, int out_size, void* d_ws, size_t ws_size,
                              hipStream_t stream) {
    const float* x  = (const float*)d_in[0];
    const float* W1 = (const float*)d_in[1];
    const float* U1 = (const float*)d_in[2];
    const float* b1 = (const float*)d_in[3];
    const float* Wd = (const float*)d_in[4];
    const float* bd = (const float*)d_in[5];
    const float* W2 = (const float*)d_in[6];
    const float* U2 = (const float*)d_in[7];
    const float* b2 = (const float*)d_in[8];
    const float* Wf = (const float*)d_in[9];
    const float* bf = (const float*)d_in[10];
    float* out = (float*)d_out;

    char* ws = (char*)d_ws;
    short* wu1_sw = (short*)(ws + WS_WU1);
    short* wu2_sw = (short*)(ws + WS_WU2);
    short* wd_sw  = (short*)(ws + WS_WD);
    float* bdp    = (float*)(ws + WS_BDP);

    precompute<<<101, 64, 0, stream>>>(W1, U1, b1, Wd, bd, W2, U2, b2,
                                       wu1_sw, wu2_sw, wd_sw, bdp);

    // DLDS=5: D[5..9] in workspace: (10-5)*32*32*2 B = 10240 B per block x 2048 blocks
    const size_t dg_need = (size_t)(T_STEPS - 5) * BTILE * DSTR * 2 * (B_TOT / BTILE);
    if (ws_size >= (size_t)WS_DG + dg_need) {
        short* Dg = (short*)(ws + WS_DG);
        lstm_all_t<5><<<B_TOT / BTILE, 256, 0, stream>>>(x, wu1_sw, wu2_sw, wd_sw,
                                                         bdp, Wf, bf, Dg, out);
    } else {
        lstm_all_t<T_STEPS><<<B_TOT / BTILE, 256, 0, stream>>>(x, wu1_sw, wu2_sw, wd_sw,
                                                               bdp, Wf, bf, (short*)ws, out);
    }
}